// Round 1
// baseline (199.522 us; speedup 1.0000x reference)
//
#include <hip/hip_runtime.h>

#define BATCH 8192
#define DIM   512
#define NLAB  128

typedef __attribute__((ext_vector_type(4))) float  f32x4;
typedef __attribute__((ext_vector_type(8))) __bf16 bf16x8;

__device__ __forceinline__ unsigned short f2bf(float x) {
  unsigned u = __float_as_uint(x);
  u = (u + 0x7FFFu + ((u >> 16) & 1u)) >> 16;   // RNE
  return (unsigned short)u;
}

__device__ __forceinline__ void load_lds16(const void* g, void* l) {
  __builtin_amdgcn_global_load_lds(
      (__attribute__((address_space(1))) void*)(g),
      (__attribute__((address_space(3))) void*)(l), 16, 0, 0);
}

// ---------------- prep: fp32 -> bf16, row norms, label histogram ----------------
__global__ __launch_bounds__(256) void prep_kernel(
    const float* __restrict__ X, const int* __restrict__ labels,
    unsigned short* __restrict__ Xb, float* __restrict__ sq,
    int* __restrict__ hist) {
  int wave = threadIdx.x >> 6, lane = threadIdx.x & 63;
  int row = blockIdx.x * 4 + wave;             // 2048 blocks * 4 waves = 8192 rows
  const float4* xr = (const float4*)(X + (size_t)row * DIM);
  float4 a = xr[lane * 2];
  float4 b = xr[lane * 2 + 1];
  float s = a.x*a.x + a.y*a.y + a.z*a.z + a.w*a.w
          + b.x*b.x + b.y*b.y + b.z*b.z + b.w*b.w;
  uint4 p;
  p.x = (unsigned)f2bf(a.x) | ((unsigned)f2bf(a.y) << 16);
  p.y = (unsigned)f2bf(a.z) | ((unsigned)f2bf(a.w) << 16);
  p.z = (unsigned)f2bf(b.x) | ((unsigned)f2bf(b.y) << 16);
  p.w = (unsigned)f2bf(b.z) | ((unsigned)f2bf(b.w) << 16);
  ((uint4*)(Xb + (size_t)row * DIM))[lane] = p;
  #pragma unroll
  for (int off = 32; off > 0; off >>= 1) s += __shfl_down(s, off);
  if (lane == 0) {
    sq[row] = s;
    atomicAdd(&hist[labels[row] & (NLAB - 1)], 1);
  }
}

// ---------------- main: fused X·X^T + masked row max/min (on d^2 surrogate) ----------------
// grid: 512 blocks = 64 i-tiles x 8 j-chunks (chunk = 1024 cols = 8 subtiles of 128)
__global__ __launch_bounds__(256, 2) void triplet_mfma(
    const unsigned short* __restrict__ Xb, const float* __restrict__ sq,
    const int* __restrict__ labels,
    float* __restrict__ pos_part, float* __restrict__ neg_part) {
  __shared__ __align__(16) unsigned short Asm[128 * 64];  // 16 KB
  __shared__ __align__(16) unsigned short Bsm[128 * 64];  // 16 KB
  __shared__ float sqj_s[1024];
  __shared__ int   labj_s[1024];
  __shared__ int   labi_s[128];

  int tid = threadIdx.x;
  int bid = blockIdx.x;
  int It = bid & 63, jc = bid >> 6;
  int i0 = It * 128, jbase = jc * 1024;

  for (int t = tid; t < 1024; t += 256) {
    sqj_s[t]  = sq[jbase + t];
    labj_s[t] = labels[jbase + t];
  }
  if (tid < 128) labi_s[tid] = labels[i0 + tid];
  __syncthreads();

  int wave = tid >> 6, lane = tid & 63;
  int wm = wave >> 1, wn = wave & 1;       // 2x2 wave grid, 64x64 per wave
  int quad = lane >> 4, lc = lane & 15;

  int labi_r[16];
  #pragma unroll
  for (int mi = 0; mi < 4; mi++)
    #pragma unroll
    for (int r = 0; r < 4; r++)
      labi_r[mi * 4 + r] = labi_s[wm * 64 + mi * 16 + quad * 4 + r];

  // running max/min of v = sq_j - 2*dot (sq_i added at the end; monotone in d^2)
  float rpos[16], rneg[16];
  #pragma unroll
  for (int t = 0; t < 16; t++) { rpos[t] = -3e38f; rneg[t] = 3e38f; }

  for (int js = 0; js < 8; js++) {
    int j0loc = js * 128;
    f32x4 acc[4][4];
    #pragma unroll
    for (int mi = 0; mi < 4; mi++)
      #pragma unroll
      for (int ni = 0; ni < 4; ni++)
        acc[mi][ni] = (f32x4){0.f, 0.f, 0.f, 0.f};

    for (int k0 = 0; k0 < DIM; k0 += 64) {
      // stage A[128][64] and B[128][64] bf16 slices; 16B/lane, wave-uniform LDS base
      #pragma unroll
      for (int t = 0; t < 4; t++) {
        int c = wave * 4 + t;                 // 16 chunks of 8 rows
        int row = c * 8 + (lane >> 3);
        int cole = (lane & 7) * 8;            // element offset within 64-wide slice
        load_lds16(Xb + (size_t)(i0 + row) * DIM + k0 + cole, &Asm[c * 512]);
        load_lds16(Xb + (size_t)(jbase + j0loc + row) * DIM + k0 + cole, &Bsm[c * 512]);
      }
      __syncthreads();
      #pragma unroll
      for (int kk = 0; kk < 64; kk += 32) {
        bf16x8 af[4], bfr[4];
        #pragma unroll
        for (int mi = 0; mi < 4; mi++)
          af[mi] = *(const bf16x8*)&Asm[(wm * 64 + mi * 16 + lc) * 64 + kk + quad * 8];
        #pragma unroll
        for (int ni = 0; ni < 4; ni++)
          bfr[ni] = *(const bf16x8*)&Bsm[(wn * 64 + ni * 16 + lc) * 64 + kk + quad * 8];
        #pragma unroll
        for (int mi = 0; mi < 4; mi++)
          #pragma unroll
          for (int ni = 0; ni < 4; ni++)
            acc[mi][ni] = __builtin_amdgcn_mfma_f32_16x16x32_bf16(
                af[mi], bfr[ni], acc[mi][ni], 0, 0, 0);
      }
      __syncthreads();
    }

    // epilogue: masked running max/min on v = sq_j - 2*dot
    // (diagonal skip omitted intentionally: diag d^2 ~ 0 never beats a real
    //  positive d^2 ~ 1024; rows w/o real positives are invalidated by hist)
    float sqj_r[4]; int labj_r[4];
    #pragma unroll
    for (int ni = 0; ni < 4; ni++) {
      int jj = j0loc + wn * 64 + ni * 16 + lc;
      sqj_r[ni]  = sqj_s[jj];
      labj_r[ni] = labj_s[jj];
    }
    #pragma unroll
    for (int mi = 0; mi < 4; mi++) {
      #pragma unroll
      for (int r = 0; r < 4; r++) {
        int li = labi_r[mi * 4 + r];
        float rp = rpos[mi * 4 + r], rn = rneg[mi * 4 + r];
        #pragma unroll
        for (int ni = 0; ni < 4; ni++) {
          float v = fmaf(-2.f, acc[mi][ni][r], sqj_r[ni]);
          bool same_l = (li == labj_r[ni]);
          rp = fmaxf(rp, same_l ? v : -3e38f);
          rn = fminf(rn, same_l ? 3e38f : v);
        }
        rpos[mi * 4 + r] = rp; rneg[mi * 4 + r] = rn;
      }
    }
  }

  // reduce across the 16 lanes of each quad (cols), xor masks 1,2,4,8
  #pragma unroll
  for (int m = 1; m <= 8; m <<= 1) {
    #pragma unroll
    for (int t = 0; t < 16; t++) {
      rpos[t] = fmaxf(rpos[t], __shfl_xor(rpos[t], m));
      rneg[t] = fminf(rneg[t], __shfl_xor(rneg[t], m));
    }
  }

  if (lc == 0) {
    int slot = jc * 2 + wn;                   // 16 partial slots
    #pragma unroll
    for (int mi = 0; mi < 4; mi++)
      #pragma unroll
      for (int r = 0; r < 4; r++) {
        int row = i0 + wm * 64 + mi * 16 + quad * 4 + r;
        pos_part[slot * BATCH + row] = rpos[mi * 4 + r];
        neg_part[slot * BATCH + row] = rneg[mi * 4 + r];
      }
  }
}

// ---------------- final: combine partials, sqrt, relu, masked mean ----------------
__global__ __launch_bounds__(256) void final_kernel(
    const float* __restrict__ pos_part, const float* __restrict__ neg_part,
    const float* __restrict__ sq, const int* __restrict__ labels,
    const int* __restrict__ hist, float* __restrict__ out) {
  float lsum = 0.f, lcnt = 0.f;
  for (int i = threadIdx.x; i < BATCH; i += 256) {
    float p = -3e38f, n = 3e38f;
    #pragma unroll
    for (int s = 0; s < 16; s++) {
      p = fmaxf(p, pos_part[s * BATCH + i]);
      n = fminf(n, neg_part[s * BATCH + i]);
    }
    float si = sq[i];
    float dp = sqrtf(fmaxf(si + p, 0.f) + 1e-16f);
    float dn = sqrtf(fmaxf(si + n, 0.f) + 1e-16f);
    int c = hist[labels[i] & (NLAB - 1)];
    if (c >= 2 && c < BATCH) {
      lsum += fmaxf(dp - dn + 0.3f, 0.f);
      lcnt += 1.f;
    }
  }
  #pragma unroll
  for (int off = 32; off > 0; off >>= 1) {
    lsum += __shfl_down(lsum, off);
    lcnt += __shfl_down(lcnt, off);
  }
  __shared__ float ss[4], sc[4];
  int wave = threadIdx.x >> 6, lane = threadIdx.x & 63;
  if (lane == 0) { ss[wave] = lsum; sc[wave] = lcnt; }
  __syncthreads();
  if (threadIdx.x == 0) {
    float S = ss[0] + ss[1] + ss[2] + ss[3];
    float C = sc[0] + sc[1] + sc[2] + sc[3];
    out[0] = S / fmaxf(C, 1.f);
  }
}

extern "C" void kernel_launch(void* const* d_in, const int* in_sizes, int n_in,
                              void* d_out, int out_size, void* d_ws, size_t ws_size,
                              hipStream_t stream) {
  const float* X      = (const float*)d_in[0];
  const int*   labels = (const int*)d_in[1];
  float* out = (float*)d_out;
  char* ws = (char*)d_ws;

  unsigned short* Xb  = (unsigned short*)ws;                               // 8 MB
  float* sq           = (float*)(ws + (8u << 20));                          // 32 KB
  int*   hist         = (int*)  (ws + (8u << 20) + (32u << 10));            // 512 B
  float* pos_part     = (float*)(ws + (8u << 20) + (64u << 10));            // 512 KB
  float* neg_part     = (float*)(ws + (8u << 20) + (64u << 10) + (512u << 10)); // 512 KB

  hipMemsetAsync(hist, 0, NLAB * sizeof(int), stream);
  prep_kernel<<<BATCH / 4, 256, 0, stream>>>(X, labels, Xb, sq, hist);
  triplet_mfma<<<512, 256, 0, stream>>>(Xb, sq, labels, pos_part, neg_part);
  final_kernel<<<1, 256, 0, stream>>>(pos_part, neg_part, sq, labels, hist, out);
}